// Round 1
// 339.295 us; speedup vs baseline: 1.2259x; 1.2259x over previous
//
#include <hip/hip_runtime.h>
#include <hip/hip_fp16.h>

// AdderNet forward:  x[256,1,64,64] -> adder(w1)+BN+ReLU -> adder(w2)+BN+ReLU
//                    -> avgpool -> FC -> out[256,10]
// R6: packed-fp16 attack on k_layer2 (was VALU-issue-bound at ~48% true issue;
//     derived VALUBusy 96.6% is the gfx94x 4-cyc formula, 2x inflated on
//     gfx950 SIMD-32).
//   - core math in VOP3P half2: pk_sub + and(abs) + pk_add = 3 instr per
//     2 output positions (1.5/tap vs 2.0 fp32); v_alignbit builds the
//     shifted packed pairs, shared across all 8 output channels
//   - one-pass layout: 4 waves x 8 output channels each, 4 cols/thread
//     (halves LDS reads/tap, removes the duplicated og-half pass)
//   - sh tile fp16 (rows padded to 68 halves for 8B-aligned b64 reads):
//     LDS 28.2KB -> 15.6KB => 8 blocks/CU (32 waves, was 20)
//   - a2 stored fp16: halves k_poolfc HBM traffic and k_layer2 WRITE_SIZE
//   - weights pre-broadcast to half2 dwords (w2b, prepped in k_stats1
//     block 0) so inner loop keeps them in SGPRs via s_load

#define BATCH 256
#define HW 4096

__device__ __forceinline__ uint32_t pk_absdiff(uint32_t a, uint32_t w) {
  __half2 av = *reinterpret_cast<const __half2*>(&a);
  __half2 wv = *reinterpret_cast<const __half2*>(&w);
  __half2 d = __hsub2(av, wv);
  return (*reinterpret_cast<uint32_t*>(&d)) & 0x7fff7fffu;
}
__device__ __forceinline__ uint32_t pk_add2(uint32_t a, uint32_t b) {
  __half2 av = *reinterpret_cast<const __half2*>(&a);
  __half2 bv = *reinterpret_cast<const __half2*>(&b);
  __half2 s = __hadd2(av, bv);
  return *reinterpret_cast<uint32_t*>(&s);
}

// ---------------- Kernel 1: layer-1 stats (sum, sumsq per channel) ----------
// + block 0 prepares w2b: w2 as broadcast half2 dwords, layout [og][c][o][t]
__global__ __launch_bounds__(256) void k_stats1(const float* __restrict__ x,
                                                const float* __restrict__ w1,
                                                double* __restrict__ s1,
                                                const float* __restrict__ w2,
                                                uint32_t* __restrict__ w2b) {
  __shared__ float sx[66 * 66];
  __shared__ float red[4 * 16 * 2];
  int b = blockIdx.x, tid = threadIdx.x;

  if (b == 0) {  // weight prep: 32*144 = 4608 entries, 18 per thread
    for (int i = tid; i < 32 * 144; i += 256) {
      int oc = i / 144;
      int rem = i - oc * 144;
      int c = rem / 9, t = rem - c * 9;
      int og = oc >> 3, o = oc & 7;
      __half h = __float2half(w2[i]);  // w2 linear layout [oc][c][t]
      uint32_t hu = *reinterpret_cast<uint16_t*>(&h);
      w2b[(og * 16 + c) * 72 + o * 9 + t] = (hu << 16) | hu;
    }
  }

  const float* xb = x + b * HW;
  for (int i = tid; i < 66 * 66; i += 256) {
    int r = i / 66, cc = i - r * 66;
    int ry = r - 1, rx = cc - 1;
    sx[i] = (ry >= 0 && ry < 64 && rx >= 0 && rx < 64) ? xb[ry * 64 + rx] : 0.f;
  }
  __syncthreads();
  float tsum[16], tsq[16];
#pragma unroll
  for (int c = 0; c < 16; c++) { tsum[c] = 0.f; tsq[c] = 0.f; }
  for (int g = 0; g < 2; g++) {
    float wv[8][9];
#pragma unroll
    for (int c = 0; c < 8; c++)
#pragma unroll
      for (int t = 0; t < 9; t++) wv[c][t] = w1[(g * 8 + c) * 9 + t];
    for (int p = 0; p < 16; p++) {
      int pix = tid + p * 256;
      int y = pix >> 6, xx = pix & 63;
      float pa[9];
#pragma unroll
      for (int dy = 0; dy < 3; dy++)
#pragma unroll
        for (int dx = 0; dx < 3; dx++)
          pa[dy * 3 + dx] = sx[(y + dy) * 66 + xx + dx];
#pragma unroll
      for (int c = 0; c < 8; c++) {
        float acc = 0.f;
#pragma unroll
        for (int t = 0; t < 9; t++) acc += fabsf(pa[t] - wv[c][t]);
        float v = -acc;
        tsum[g * 8 + c] += v;
        tsq[g * 8 + c] += v * v;
      }
    }
  }
  int lane = tid & 63, wid = tid >> 6;
#pragma unroll
  for (int c = 0; c < 16; c++) {
    float s = tsum[c], q = tsq[c];
    for (int off = 32; off; off >>= 1) {
      s += __shfl_down(s, off, 64);
      q += __shfl_down(q, off, 64);
    }
    if (lane == 0) { red[(wid * 16 + c) * 2] = s; red[(wid * 16 + c) * 2 + 1] = q; }
  }
  __syncthreads();
  if (tid < 16) {
    float s = red[tid * 2] + red[(16 + tid) * 2] + red[(32 + tid) * 2] + red[(48 + tid) * 2];
    float q = red[tid * 2 + 1] + red[(16 + tid) * 2 + 1] + red[(32 + tid) * 2 + 1] +
              red[(48 + tid) * 2 + 1];
    atomicAdd(&s1[tid], (double)s);
    atomicAdd(&s1[16 + tid], (double)q);
  }
}

// ---------------- Kernel 2: layer 2 (the heavy one) -------------------------
// Block = (image b, 4-row band). Stage 0: inline BN1 params. Stage 1: h1 tile
// (fp16, rows y0-1..y0+4, cols -1..64, row stride 68) into LDS. Stage 2: each
// wave owns 8 output channels over the whole band; 4 cols/thread; packed-fp16
// inner loop (3 VOP3P per 2 positions), fp16 accumulators (magnitude <= ~300,
// per-pixel RMS err ~0.3 pre-BN, washed out by the 4096-px pool).
__global__ __launch_bounds__(256, 8) void k_layer2(
    const float* __restrict__ x, const float* __restrict__ w1,
    const double* __restrict__ s1, const float* __restrict__ g1,
    const float* __restrict__ b1, const uint32_t* __restrict__ w2b,
    __half* __restrict__ a2, double* __restrict__ s2) {
  __shared__ float sxt[8 * 68];                    // x rows y0-2..y0+5, cols -2..65
  __shared__ __align__(16) __half sh[16 * 6 * 68]; // h1 [c][row][col -1..64], pad to 68
  __shared__ float red[4 * 16];                    // per-wave (s,q) per o
  __shared__ float sc1s[16], sf1s[16];
  int blk = blockIdx.x;
  int b = blk >> 4, rb = blk & 15;
  int y0 = rb * 4;
  int tid = threadIdx.x;

  if (tid < 16) {  // inline BN1 params (block-redundant)
    double N = 1048576.0;
    double mean = s1[tid] / N;
    double var = s1[16 + tid] / N - mean * mean;
    float inv = (float)(1.0 / sqrt(var + 1e-5));
    float sc = g1[tid] * inv;
    sc1s[tid] = sc;
    sf1s[tid] = b1[tid] - (float)mean * sc;
  }
  const float* xb = x + b * HW;
  for (int i = tid; i < 8 * 68; i += 256) {
    int r = i / 68, cc = i - r * 68;
    int ry = y0 + r - 2, rx = cc - 2;
    sxt[i] = (ry >= 0 && ry < 64 && rx >= 0 && rx < 64) ? xb[ry * 64 + rx] : 0.f;
  }
  __syncthreads();
  // h1 recompute in fp32 (same order as k_stats1), rounded to fp16 on store
  for (int c = 0; c < 16; c++) {
    float wv[9];
#pragma unroll
    for (int t = 0; t < 9; t++) wv[t] = w1[c * 9 + t];
    float sc = sc1s[c], sf = sf1s[c];
    for (int i = tid; i < 396; i += 256) {
      int r = i / 66, col = i - r * 66;
      int y = y0 + r - 1, xx = col - 1;
      float v = 0.f;  // h1 padding is post-activation zero
      if (y >= 0 && y < 64 && xx >= 0 && xx < 64) {
        float acc = 0.f;
#pragma unroll
        for (int dy = 0; dy < 3; dy++)
#pragma unroll
          for (int dx = 0; dx < 3; dx++)
            acc += fabsf(sxt[(r + dy) * 68 + col + dx] - wv[dy * 3 + dx]);
        v = fmaxf(fmaf(-acc, sc, sf), 0.f);
      }
      sh[c * 408 + r * 68 + col] = __float2half(v);
    }
  }
  __syncthreads();

  int lane = tid & 63;
  int wid = __builtin_amdgcn_readfirstlane(tid >> 6);  // wave id -> og group
  int r = lane >> 4;          // row within band, 0..3
  int x0 = (lane & 15) << 2;  // 4 output cols per thread, 8B-aligned LDS reads
  const __half* shb = &sh[r * 68 + x0];
  const uint32_t* wb = w2b + wid * (16 * 72);

  // packed accumulators: acc[o][0] = positions (x0, x0+1), [1] = (x0+2, x0+3)
  uint32_t acc[8][2];
#pragma unroll
  for (int o = 0; o < 8; o++) { acc[o][0] = 0u; acc[o][1] = 0u; }

#pragma unroll 2
  for (int c = 0; c < 16; c++) {
    const __half* rp = shb + c * 408;
    uint32_t q0[3], q1[3], q2[3];
#pragma unroll
    for (int dy = 0; dy < 3; dy++) {
      uint2 t2 = *reinterpret_cast<const uint2*>(rp + dy * 68);  // a0..a3
      q0[dy] = t2.x;
      q1[dy] = t2.y;
      q2[dy] = *reinterpret_cast<const uint32_t*>(rp + dy * 68 + 4);  // a4,a5
    }
    uint32_t s0[3], s1v[3];
#pragma unroll
    for (int dy = 0; dy < 3; dy++) {
      s0[dy] = __builtin_amdgcn_alignbit(q1[dy], q0[dy], 16);   // (a1,a2)
      s1v[dy] = __builtin_amdgcn_alignbit(q2[dy], q1[dy], 16);  // (a3,a4)
    }
    const uint32_t* wc = wb + c * 72;  // uniform -> s_load
#pragma unroll
    for (int o = 0; o < 8; o++) {
#pragma unroll
      for (int dy = 0; dy < 3; dy++) {
        uint32_t wa = wc[o * 9 + dy * 3];
        uint32_t wbv = wc[o * 9 + dy * 3 + 1];
        uint32_t wcv = wc[o * 9 + dy * 3 + 2];
        acc[o][0] = pk_add2(acc[o][0], pk_absdiff(q0[dy], wa));
        acc[o][0] = pk_add2(acc[o][0], pk_absdiff(s0[dy], wbv));
        acc[o][0] = pk_add2(acc[o][0], pk_absdiff(q1[dy], wcv));
        acc[o][1] = pk_add2(acc[o][1], pk_absdiff(q1[dy], wa));
        acc[o][1] = pk_add2(acc[o][1], pk_absdiff(s1v[dy], wbv));
        acc[o][1] = pk_add2(acc[o][1], pk_absdiff(q2[dy], wcv));
      }
    }
  }

  // store (negated) + per-wave stats partials; each wave covers the full band
  __half* a2b = a2 + ((size_t)b * 32 + wid * 8) * HW + (y0 + r) * 64 + x0;
#pragma unroll
  for (int o = 0; o < 8; o++) {
    uint32_t n0 = acc[o][0] ^ 0x80008000u;
    uint32_t n1 = acc[o][1] ^ 0x80008000u;
    *reinterpret_cast<uint2*>(a2b + o * HW) = make_uint2(n0, n1);
    float2 f0 = __half22float2(*reinterpret_cast<__half2*>(&n0));
    float2 f1 = __half22float2(*reinterpret_cast<__half2*>(&n1));
    float s = f0.x + f0.y + f1.x + f1.y;
    float q = f0.x * f0.x + f0.y * f0.y + f1.x * f1.x + f1.y * f1.y;
    for (int off = 32; off; off >>= 1) {
      s += __shfl_down(s, off, 64);
      q += __shfl_down(q, off, 64);
    }
    if (lane == 0) { red[wid * 16 + o * 2] = s; red[wid * 16 + o * 2 + 1] = q; }
  }
  __syncthreads();
  if (tid < 32) {  // wave (tid>>3) owns outputs (tid>>3)*8 + (tid&7)
    float s = red[(tid >> 3) * 16 + (tid & 7) * 2];
    float q = red[(tid >> 3) * 16 + (tid & 7) * 2 + 1];
    atomicAdd(&s2[tid], (double)s);
    atomicAdd(&s2[32 + tid], (double)q);
  }
}

// ---------------- Kernel 3: BN2 (inline params) + ReLU + avgpool + FC -------
__global__ __launch_bounds__(1024) void k_poolfc(const __half* __restrict__ a2,
                                                 const double* __restrict__ s2,
                                                 const float* __restrict__ g2,
                                                 const float* __restrict__ b2,
                                                 const float* __restrict__ fw,
                                                 const float* __restrict__ fb,
                                                 float* __restrict__ out) {
  __shared__ float sc2s[32], sf2s[32];
  __shared__ float poolv[32];
  int b = blockIdx.x, tid = threadIdx.x;
  if (tid < 32) {  // inline BN2 params (block-redundant)
    double N = 1048576.0;
    double mean = s2[tid] / N;
    double var = s2[32 + tid] / N - mean * mean;
    float inv = (float)(1.0 / sqrt(var + 1e-5));
    float sc = g2[tid] * inv;
    sc2s[tid] = sc;
    sf2s[tid] = b2[tid] - (float)mean * sc;
  }
  __syncthreads();
  int o = tid >> 5, part = tid & 31;  // 32 threads per channel
  const uint4* p = (const uint4*)(a2 + ((size_t)b * 32 + o) * HW);
  float s = sc2s[o], f = sf2s[o];
  float acc = 0.f;
#pragma unroll
  for (int i = 0; i < 16; i++) {  // 16 iters * 32 threads * 8 halves = 4096
    uint4 v = p[i * 32 + part];
    float2 f0 = __half22float2(*reinterpret_cast<const __half2*>(&v.x));
    float2 f1 = __half22float2(*reinterpret_cast<const __half2*>(&v.y));
    float2 f2 = __half22float2(*reinterpret_cast<const __half2*>(&v.z));
    float2 f3 = __half22float2(*reinterpret_cast<const __half2*>(&v.w));
    acc += fmaxf(fmaf(f0.x, s, f), 0.f) + fmaxf(fmaf(f0.y, s, f), 0.f) +
           fmaxf(fmaf(f1.x, s, f), 0.f) + fmaxf(fmaf(f1.y, s, f), 0.f) +
           fmaxf(fmaf(f2.x, s, f), 0.f) + fmaxf(fmaf(f2.y, s, f), 0.f) +
           fmaxf(fmaf(f3.x, s, f), 0.f) + fmaxf(fmaf(f3.y, s, f), 0.f);
  }
  acc += __shfl_down(acc, 16, 32);
  acc += __shfl_down(acc, 8, 32);
  acc += __shfl_down(acc, 4, 32);
  acc += __shfl_down(acc, 2, 32);
  acc += __shfl_down(acc, 1, 32);
  if (part == 0) poolv[o] = acc * (1.f / 4096.f);
  __syncthreads();
  if (tid < 10) {
    float rr = fb[tid];
#pragma unroll
    for (int oc = 0; oc < 32; oc++) rr += poolv[oc] * fw[tid * 32 + oc];
    out[b * 10 + tid] = rr;
  }
}

extern "C" void kernel_launch(void* const* d_in, const int* in_sizes, int n_in,
                              void* d_out, int out_size, void* d_ws, size_t ws_size,
                              hipStream_t stream) {
  const float* x   = (const float*)d_in[0];
  const float* w1  = (const float*)d_in[1];
  const float* g1  = (const float*)d_in[2];
  const float* b1  = (const float*)d_in[3];
  const float* w2  = (const float*)d_in[4];
  const float* g2  = (const float*)d_in[5];
  const float* b2  = (const float*)d_in[6];
  const float* fcw = (const float*)d_in[7];
  const float* fcb = (const float*)d_in[8];
  float* out = (float*)d_out;

  char* ws = (char*)d_ws;
  __half* a2 = (__half*)ws;                                // 67,108,864 B
  double* stats = (double*)(ws + 67108864);                // 96 doubles
  double* s1 = stats;                                      // sum[16], sq[16]
  double* s2 = stats + 32;                                 // sum[32], sq[32]
  uint32_t* w2b = (uint32_t*)(ws + 67108864 + 1024);       // 4608 dwords

  hipMemsetAsync(stats, 0, 768, stream);
  k_stats1<<<256, 256, 0, stream>>>(x, w1, s1, w2, w2b);
  k_layer2<<<4096, 256, 0, stream>>>(x, w1, s1, g1, b1, w2b, a2, s2);
  k_poolfc<<<256, 1024, 0, stream>>>(a2, s2, g2, b2, fcw, fcb, out);
}

// Round 2
// 234.965 us; speedup vs baseline: 1.7702x; 1.4440x over previous
//
#include <hip/hip_runtime.h>
#include <hip/hip_fp16.h>

// AdderNet forward:  x[256,1,64,64] -> adder(w1)+BN+ReLU -> adder(w2)+BN+ReLU
//                    -> avgpool -> FC -> out[256,10]
// R7: v_sad_u16 attack on k_layer2's inner loop.
//   - R6 post-mortem: ~40% true VALU issue at 73% occupancy => structural
//     per-wave stalls; the lever that always pays is instruction count.
//   - quantize h1 and w2 to u16 fixed point q(v)=(v+1)*4096 (offset cancels
//     in |a-w|, scale factors out). v_sad_u16 = |lo-lo|+|hi-hi|+acc: 2 taps
//     + accumulate per instruction (was 3 instr / 2 taps in packed fp16).
//   - 9 taps/position = 4 pair-sads + 1 zero-extended single-sad; shifted
//     pairs via v_alignbit, cross-row leftover pairs via v_perm_b32.
//   - integer-exact accumulation; more precise than R6's fp16 chain.
//   - acc[8][4] u32 => ~72 VGPR => __launch_bounds__(256,6).

#define BATCH 256
#define HW 4096

__device__ __forceinline__ uint32_t sad16(uint32_t a, uint32_t b, uint32_t c) {
#if __has_builtin(__builtin_amdgcn_sad_u16)
  return __builtin_amdgcn_sad_u16(a, b, c);
#else
  uint32_t d;
  asm("v_sad_u16 %0, %1, %2, %3" : "=v"(d) : "v"(a), "v"(b), "v"(c));
  return d;
#endif
}

// ---------------- Kernel 1: layer-1 stats (sum, sumsq per channel) ----------
// + block 0 prepares w2b: u16-quantized w2 packed for the sad layout:
//   per (og,c,o): 5 dwords = (w00,w01) (w10,w11) (w20,w21) (w02,w12) (w22,0)
__global__ __launch_bounds__(256) void k_stats1(const float* __restrict__ x,
                                                const float* __restrict__ w1,
                                                double* __restrict__ s1,
                                                const float* __restrict__ w2,
                                                uint32_t* __restrict__ w2b) {
  __shared__ float sx[66 * 66];
  __shared__ float red[4 * 16 * 2];
  int b = blockIdx.x, tid = threadIdx.x;

  if (b == 0) {  // weight prep: 512 (oc,c) items, 5 dwords each
    for (int i = tid; i < 512; i += 256) {
      int oc = i >> 4, c = i & 15;
      int og = oc >> 3, o = oc & 7;
      const float* wp = w2 + (oc * 16 + c) * 9;
      uint32_t q[9];
#pragma unroll
      for (int t = 0; t < 9; t++) {
        float qf = rintf(fmaf(wp[t], 4096.f, 4096.f));
        q[t] = (uint32_t)fminf(fmaxf(qf, 0.f), 65535.f);
      }
      uint32_t* dst = w2b + ((og * 16 + c) * 8 + o) * 5;
      dst[0] = q[0] | (q[1] << 16);
      dst[1] = q[3] | (q[4] << 16);
      dst[2] = q[6] | (q[7] << 16);
      dst[3] = q[2] | (q[5] << 16);  // leftover pair rows 0,1 (dx=2)
      dst[4] = q[8];                 // leftover single row 2 (zero-extended)
    }
  }

  const float* xb = x + b * HW;
  for (int i = tid; i < 66 * 66; i += 256) {
    int r = i / 66, cc = i - r * 66;
    int ry = r - 1, rx = cc - 1;
    sx[i] = (ry >= 0 && ry < 64 && rx >= 0 && rx < 64) ? xb[ry * 64 + rx] : 0.f;
  }
  __syncthreads();
  float tsum[16], tsq[16];
#pragma unroll
  for (int c = 0; c < 16; c++) { tsum[c] = 0.f; tsq[c] = 0.f; }
  for (int g = 0; g < 2; g++) {
    float wv[8][9];
#pragma unroll
    for (int c = 0; c < 8; c++)
#pragma unroll
      for (int t = 0; t < 9; t++) wv[c][t] = w1[(g * 8 + c) * 9 + t];
    for (int p = 0; p < 16; p++) {
      int pix = tid + p * 256;
      int y = pix >> 6, xx = pix & 63;
      float pa[9];
#pragma unroll
      for (int dy = 0; dy < 3; dy++)
#pragma unroll
        for (int dx = 0; dx < 3; dx++)
          pa[dy * 3 + dx] = sx[(y + dy) * 66 + xx + dx];
#pragma unroll
      for (int c = 0; c < 8; c++) {
        float acc = 0.f;
#pragma unroll
        for (int t = 0; t < 9; t++) acc += fabsf(pa[t] - wv[c][t]);
        float v = -acc;
        tsum[g * 8 + c] += v;
        tsq[g * 8 + c] += v * v;
      }
    }
  }
  int lane = tid & 63, wid = tid >> 6;
#pragma unroll
  for (int c = 0; c < 16; c++) {
    float s = tsum[c], q = tsq[c];
    for (int off = 32; off; off >>= 1) {
      s += __shfl_down(s, off, 64);
      q += __shfl_down(q, off, 64);
    }
    if (lane == 0) { red[(wid * 16 + c) * 2] = s; red[(wid * 16 + c) * 2 + 1] = q; }
  }
  __syncthreads();
  if (tid < 16) {
    float s = red[tid * 2] + red[(16 + tid) * 2] + red[(32 + tid) * 2] + red[(48 + tid) * 2];
    float q = red[tid * 2 + 1] + red[(16 + tid) * 2 + 1] + red[(32 + tid) * 2 + 1] +
              red[(48 + tid) * 2 + 1];
    atomicAdd(&s1[tid], (double)s);
    atomicAdd(&s1[16 + tid], (double)q);
  }
}

// ---------------- Kernel 2: layer 2 (the heavy one) -------------------------
// Block = (image b, 4-row band). h1 tile recomputed in fp32 (same summation
// order as k_stats1), quantized to u16 on store. Main loop: per c, load 6
// packed activations per thread, build shifted/leftover packs, then 8 o x
// 4 positions x 5 v_sad_u16 (2 taps + acc each). Integer-exact accumulation.
__global__ __launch_bounds__(256, 6) void k_layer2(
    const float* __restrict__ x, const float* __restrict__ w1,
    const double* __restrict__ s1, const float* __restrict__ g1,
    const float* __restrict__ b1, const uint32_t* __restrict__ w2b,
    __half* __restrict__ a2, double* __restrict__ s2) {
  __shared__ float sxt[8 * 68];                         // x rows y0-2..y0+5
  __shared__ __align__(16) unsigned short sh[16 * 408]; // h1q [c][row][col -1..64], stride 68
  __shared__ float red[4 * 16];
  __shared__ float sc1s[16], sf1s[16];
  int blk = blockIdx.x;
  int b = blk >> 4, rb = blk & 15;
  int y0 = rb * 4;
  int tid = threadIdx.x;

  if (tid < 16) {  // inline BN1 params (block-redundant)
    double N = 1048576.0;
    double mean = s1[tid] / N;
    double var = s1[16 + tid] / N - mean * mean;
    float inv = (float)(1.0 / sqrt(var + 1e-5));
    float sc = g1[tid] * inv;
    sc1s[tid] = sc;
    sf1s[tid] = b1[tid] - (float)mean * sc;
  }
  const float* xb = x + b * HW;
  for (int i = tid; i < 8 * 68; i += 256) {
    int r = i / 68, cc = i - r * 68;
    int ry = y0 + r - 2, rx = cc - 2;
    sxt[i] = (ry >= 0 && ry < 64 && rx >= 0 && rx < 64) ? xb[ry * 64 + rx] : 0.f;
  }
  __syncthreads();
  // h1 recompute in fp32 (same order as k_stats1), quantize u16 on store.
  // q(v) = (v+1)*4096, round-half-up; padding (v=0) maps to 4096.
  for (int c = 0; c < 16; c++) {
    float wv[9];
#pragma unroll
    for (int t = 0; t < 9; t++) wv[t] = w1[c * 9 + t];
    float sc = sc1s[c], sf = sf1s[c];
    for (int i = tid; i < 396; i += 256) {
      int r = i / 66, col = i - r * 66;
      int y = y0 + r - 1, xx = col - 1;
      float v = 0.f;  // h1 padding is post-activation zero
      if (y >= 0 && y < 64 && xx >= 0 && xx < 64) {
        float acc = 0.f;
#pragma unroll
        for (int dy = 0; dy < 3; dy++)
#pragma unroll
          for (int dx = 0; dx < 3; dx++)
            acc += fabsf(sxt[(r + dy) * 68 + col + dx] - wv[dy * 3 + dx]);
        v = fmaxf(fmaf(-acc, sc, sf), 0.f);
      }
      sh[c * 408 + r * 68 + col] =
          (unsigned short)fminf(fmaf(v, 4096.f, 4096.5f), 65535.f);
    }
  }
  __syncthreads();

  int lane = tid & 63;
  int wid4 = tid >> 6;
  int wofs = __builtin_amdgcn_readfirstlane(wid4 * 640);  // og weight base
  int r = lane >> 4;          // row within band, 0..3
  int x0 = (lane & 15) << 2;  // 4 output cols per thread
  const unsigned short* shb = sh + r * 68 + x0;

  uint32_t acc[8][4];
#pragma unroll
  for (int o = 0; o < 8; o++)
#pragma unroll
    for (int p = 0; p < 4; p++) acc[o][p] = 0u;

#pragma unroll 1
  for (int c = 0; c < 16; c++) {
    const unsigned short* rp = shb + c * 408;
    uint32_t d0[3], d1[3], d2[3], s01[3], s23[3];
#pragma unroll
    for (int dy = 0; dy < 3; dy++) {
      uint2 t2 = *reinterpret_cast<const uint2*>(rp + dy * 68);  // a0..a3
      d0[dy] = t2.x;
      d1[dy] = t2.y;
      d2[dy] = *reinterpret_cast<const uint32_t*>(rp + dy * 68 + 4);  // a4,a5
      s01[dy] = __builtin_amdgcn_alignbit(d1[dy], d0[dy], 16);  // (a1,a2)
      s23[dy] = __builtin_amdgcn_alignbit(d2[dy], d1[dy], 16);  // (a3,a4)
    }
    // leftover pairs (a[0][p+2], a[1][p+2]) and singles a[2][p+2]
    uint32_t L0 = __builtin_amdgcn_perm(d1[1], d1[0], 0x05040100u);
    uint32_t L1 = __builtin_amdgcn_perm(d1[1], d1[0], 0x07060302u);
    uint32_t L2 = __builtin_amdgcn_perm(d2[1], d2[0], 0x05040100u);
    uint32_t L3 = __builtin_amdgcn_perm(d2[1], d2[0], 0x07060302u);
    uint32_t E0 = d1[2] & 0xffffu, E1 = d1[2] >> 16;
    uint32_t E2 = d2[2] & 0xffffu, E3 = d2[2] >> 16;
    const uint32_t* wc = w2b + wofs + c * 40;  // uniform -> s_load
#pragma unroll
    for (int o = 0; o < 8; o++) {
      uint32_t P0 = wc[o * 5], P1 = wc[o * 5 + 1], P2 = wc[o * 5 + 2];
      uint32_t P3 = wc[o * 5 + 3], P4 = wc[o * 5 + 4];
      acc[o][0] = sad16(d0[0], P0,
                  sad16(d0[1], P1,
                  sad16(d0[2], P2,
                  sad16(L0, P3, sad16(E0, P4, acc[o][0])))));
      acc[o][1] = sad16(s01[0], P0,
                  sad16(s01[1], P1,
                  sad16(s01[2], P2,
                  sad16(L1, P3, sad16(E1, P4, acc[o][1])))));
      acc[o][2] = sad16(d1[0], P0,
                  sad16(d1[1], P1,
                  sad16(d1[2], P2,
                  sad16(L2, P3, sad16(E2, P4, acc[o][2])))));
      acc[o][3] = sad16(s23[0], P0,
                  sad16(s23[1], P1,
                  sad16(s23[2], P2,
                  sad16(L3, P3, sad16(E3, P4, acc[o][3])))));
    }
  }

  // store (negate + rescale) + per-wave stats partials
  const float ksc = -1.f / 4096.f;
  __half* a2b = a2 + ((size_t)b * 32 + wid4 * 8) * HW + (y0 + r) * 64 + x0;
#pragma unroll
  for (int o = 0; o < 8; o++) {
    float f0 = (float)acc[o][0] * ksc, f1 = (float)acc[o][1] * ksc;
    float f2 = (float)acc[o][2] * ksc, f3 = (float)acc[o][3] * ksc;
    __half2 h01 = __floats2half2_rn(f0, f1);
    __half2 h23 = __floats2half2_rn(f2, f3);
    uint2 st = make_uint2(*reinterpret_cast<uint32_t*>(&h01),
                          *reinterpret_cast<uint32_t*>(&h23));
    *reinterpret_cast<uint2*>(a2b + o * HW) = st;
    float2 c0 = __half22float2(h01);  // stats from the stored (rounded) values
    float2 c1 = __half22float2(h23);
    float s = c0.x + c0.y + c1.x + c1.y;
    float q = c0.x * c0.x + c0.y * c0.y + c1.x * c1.x + c1.y * c1.y;
    for (int off = 32; off; off >>= 1) {
      s += __shfl_down(s, off, 64);
      q += __shfl_down(q, off, 64);
    }
    if (lane == 0) { red[wid4 * 16 + o * 2] = s; red[wid4 * 16 + o * 2 + 1] = q; }
  }
  __syncthreads();
  if (tid < 32) {  // wave (tid>>3) owns outputs (tid>>3)*8 + (tid&7)
    float s = red[(tid >> 3) * 16 + (tid & 7) * 2];
    float q = red[(tid >> 3) * 16 + (tid & 7) * 2 + 1];
    atomicAdd(&s2[tid], (double)s);
    atomicAdd(&s2[32 + tid], (double)q);
  }
}

// ---------------- Kernel 3: BN2 (inline params) + ReLU + avgpool + FC -------
__global__ __launch_bounds__(1024) void k_poolfc(const __half* __restrict__ a2,
                                                 const double* __restrict__ s2,
                                                 const float* __restrict__ g2,
                                                 const float* __restrict__ b2,
                                                 const float* __restrict__ fw,
                                                 const float* __restrict__ fb,
                                                 float* __restrict__ out) {
  __shared__ float sc2s[32], sf2s[32];
  __shared__ float poolv[32];
  int b = blockIdx.x, tid = threadIdx.x;
  if (tid < 32) {  // inline BN2 params (block-redundant)
    double N = 1048576.0;
    double mean = s2[tid] / N;
    double var = s2[32 + tid] / N - mean * mean;
    float inv = (float)(1.0 / sqrt(var + 1e-5));
    float sc = g2[tid] * inv;
    sc2s[tid] = sc;
    sf2s[tid] = b2[tid] - (float)mean * sc;
  }
  __syncthreads();
  int o = tid >> 5, part = tid & 31;  // 32 threads per channel
  const uint4* p = (const uint4*)(a2 + ((size_t)b * 32 + o) * HW);
  float s = sc2s[o], f = sf2s[o];
  float acc = 0.f;
#pragma unroll
  for (int i = 0; i < 16; i++) {  // 16 iters * 32 threads * 8 halves = 4096
    uint4 v = p[i * 32 + part];
    float2 f0 = __half22float2(*reinterpret_cast<const __half2*>(&v.x));
    float2 f1 = __half22float2(*reinterpret_cast<const __half2*>(&v.y));
    float2 f2 = __half22float2(*reinterpret_cast<const __half2*>(&v.z));
    float2 f3 = __half22float2(*reinterpret_cast<const __half2*>(&v.w));
    acc += fmaxf(fmaf(f0.x, s, f), 0.f) + fmaxf(fmaf(f0.y, s, f), 0.f) +
           fmaxf(fmaf(f1.x, s, f), 0.f) + fmaxf(fmaf(f1.y, s, f), 0.f) +
           fmaxf(fmaf(f2.x, s, f), 0.f) + fmaxf(fmaf(f2.y, s, f), 0.f) +
           fmaxf(fmaf(f3.x, s, f), 0.f) + fmaxf(fmaf(f3.y, s, f), 0.f);
  }
  acc += __shfl_down(acc, 16, 32);
  acc += __shfl_down(acc, 8, 32);
  acc += __shfl_down(acc, 4, 32);
  acc += __shfl_down(acc, 2, 32);
  acc += __shfl_down(acc, 1, 32);
  if (part == 0) poolv[o] = acc * (1.f / 4096.f);
  __syncthreads();
  if (tid < 10) {
    float rr = fb[tid];
#pragma unroll
    for (int oc = 0; oc < 32; oc++) rr += poolv[oc] * fw[tid * 32 + oc];
    out[b * 10 + tid] = rr;
  }
}

extern "C" void kernel_launch(void* const* d_in, const int* in_sizes, int n_in,
                              void* d_out, int out_size, void* d_ws, size_t ws_size,
                              hipStream_t stream) {
  const float* x   = (const float*)d_in[0];
  const float* w1  = (const float*)d_in[1];
  const float* g1  = (const float*)d_in[2];
  const float* b1  = (const float*)d_in[3];
  const float* w2  = (const float*)d_in[4];
  const float* g2  = (const float*)d_in[5];
  const float* b2  = (const float*)d_in[6];
  const float* fcw = (const float*)d_in[7];
  const float* fcb = (const float*)d_in[8];
  float* out = (float*)d_out;

  char* ws = (char*)d_ws;
  __half* a2 = (__half*)ws;                                // 67,108,864 B
  double* stats = (double*)(ws + 67108864);                // 96 doubles
  double* s1 = stats;                                      // sum[16], sq[16]
  double* s2 = stats + 32;                                 // sum[32], sq[32]
  uint32_t* w2b = (uint32_t*)(ws + 67108864 + 1024);       // 2560 dwords

  hipMemsetAsync(stats, 0, 768, stream);
  k_stats1<<<256, 256, 0, stream>>>(x, w1, s1, w2, w2b);
  k_layer2<<<4096, 256, 0, stream>>>(x, w1, s1, g1, b1, w2b, a2, s2);
  k_poolfc<<<256, 1024, 0, stream>>>(a2, s2, g2, b2, fcw, fcb, out);
}